// Round 1
// baseline (308.106 us; speedup 1.0000x reference)
//
#include <hip/hip_runtime.h>
#include <hip/hip_bf16.h>

#define Tq 4096
#define Cdim 1024
#define NH 16
#define DH 64

typedef __attribute__((ext_vector_type(8))) short short8;
typedef __attribute__((ext_vector_type(4))) float f32x4;

__device__ __forceinline__ unsigned short f2bf(float f) {
  union { float f; unsigned int u; } v; v.f = f;
  unsigned int r = v.u + 0x7FFFu + ((v.u >> 16) & 1u);
  return (unsigned short)(r >> 16);
}

// ---------------- fp32 -> bf16 convert ----------------
__global__ void cvt_kernel(const float* __restrict__ in, unsigned short* __restrict__ out, int n) {
  int idx = (blockIdx.x * blockDim.x + threadIdx.x) * 4;
  if (idx + 3 < n) {
    float4 v = *reinterpret_cast<const float4*>(in + idx);
    ushort4 o;
    o.x = f2bf(v.x); o.y = f2bf(v.y); o.z = f2bf(v.z); o.w = f2bf(v.w);
    *reinterpret_cast<ushort4*>(out + idx) = o;
  }
}

// ------------- transpose + convert: in[R][C] f32 -> out[C][R] bf16 -------------
__global__ void transpose_cvt(const float* __restrict__ in, unsigned short* __restrict__ out,
                              int R, int Ccols) {
  __shared__ float tile[64][65];
  int c0 = blockIdx.x * 64, r0 = blockIdx.y * 64;
  int tx = threadIdx.x & 63;
  int ty = threadIdx.x >> 6;   // 0..3
  #pragma unroll
  for (int rr = 0; rr < 64; rr += 4)
    tile[rr + ty][tx] = in[(r0 + rr + ty) * Ccols + c0 + tx];
  __syncthreads();
  #pragma unroll
  for (int rr = 0; rr < 64; rr += 4)
    out[(c0 + rr + ty) * R + r0 + tx] = f2bf(tile[tx][rr + ty]);
}

// ------------- GEMM: C[M][N] = A[M][K](bf16) * B^T[N][K](bf16) -------------
// OUT_MODE 0: scatter bf16 into qkv heads buffer [3][NH][Tq][DH]
// OUT_MODE 1: fp32 row-major [M][N]
template<int OUT_MODE>
__global__ __launch_bounds__(256, 2)
void gemm_bt(const unsigned short* __restrict__ A,
             const unsigned short* __restrict__ B,
             void* __restrict__ Cout,
             int M, int N, int K)
{
  __shared__ __align__(16) unsigned short As[128][72];
  __shared__ __align__(16) unsigned short Bs[128][72];
  const int tid = threadIdx.x;
  const int lane = tid & 63;
  const int wave = tid >> 6;
  const int wm = wave >> 1, wn = wave & 1;
  const int m0 = blockIdx.y * 128, n0 = blockIdx.x * 128;

  f32x4 acc[4][4] = {};

  const int srow = tid >> 3;          // 0..31
  const int scol = (tid & 7) * 8;     // element col

  for (int k0 = 0; k0 < K; k0 += 64) {
    __syncthreads();
    #pragma unroll
    for (int r = 0; r < 128; r += 32) {
      *reinterpret_cast<short8*>(&As[srow + r][scol]) =
        *reinterpret_cast<const short8*>(&A[(m0 + srow + r) * K + k0 + scol]);
      *reinterpret_cast<short8*>(&Bs[srow + r][scol]) =
        *reinterpret_cast<const short8*>(&B[(n0 + srow + r) * K + k0 + scol]);
    }
    __syncthreads();
    #pragma unroll
    for (int kk = 0; kk < 64; kk += 32) {
      const int frow = lane & 15;
      const int fcol = kk + 8 * (lane >> 4);
      short8 a[4], b[4];
      #pragma unroll
      for (int i = 0; i < 4; ++i) {
        a[i] = *reinterpret_cast<const short8*>(&As[wm * 64 + i * 16 + frow][fcol]);
        b[i] = *reinterpret_cast<const short8*>(&Bs[wn * 64 + i * 16 + frow][fcol]);
      }
      #pragma unroll
      for (int i = 0; i < 4; ++i)
        #pragma unroll
        for (int j = 0; j < 4; ++j)
          acc[i][j] = __builtin_amdgcn_mfma_f32_16x16x32_bf16(a[i], b[j], acc[i][j], 0, 0, 0);
    }
  }

  const int rbase = (lane >> 4) * 4;
  const int ccol = lane & 15;
  #pragma unroll
  for (int i = 0; i < 4; ++i) {
    #pragma unroll
    for (int j = 0; j < 4; ++j) {
      const int col = n0 + wn * 64 + j * 16 + ccol;
      #pragma unroll
      for (int r = 0; r < 4; ++r) {
        const int row = m0 + wm * 64 + i * 16 + rbase + r;
        float v = acc[i][j][r];
        if (OUT_MODE == 0) {
          unsigned short* q = (unsigned short*)Cout;
          int sec = col >> 10, rem = col & 1023;
          int hh = rem >> 6, d = rem & 63;
          q[(((sec * NH + hh) * Tq) + row) * DH + d] = f2bf(v);
        } else {
          ((float*)Cout)[row * N + col] = v;
        }
      }
    }
  }
}

// ------------- flash attention: causal + dense prefix -------------
__global__ __launch_bounds__(256, 2)
void attn_kernel(const unsigned short* __restrict__ qkv,   // [3][NH][Tq][DH] bf16
                 unsigned short* __restrict__ y,           // [Tq][Cdim] bf16
                 const int* __restrict__ nf_ptr)
{
  __shared__ __align__(16) unsigned short Ks[64][72];
  __shared__ __align__(16) unsigned short VTs[64][72];
  __shared__ __align__(16) unsigned short Ps[4][16][72];

  const int tid = threadIdx.x;
  const int lane = tid & 63;
  const int w = tid >> 6;
  const int h = blockIdx.x & (NH - 1);
  const int qt = blockIdx.x >> 4;
  const int q0 = qt * 64;
  const int nf = nf_ptr[0];

  const unsigned short* Qh = qkv + (h * Tq) * DH;
  const unsigned short* Kh = qkv + ((NH + h) * Tq) * DH;
  const unsigned short* Vh = qkv + ((2 * NH + h) * Tq) * DH;

  // Q fragments hoisted to registers
  const int qrow_a = q0 + w * 16 + (lane & 15);
  short8 qf[2];
  #pragma unroll
  for (int kk = 0; kk < 2; ++kk)
    qf[kk] = *reinterpret_cast<const short8*>(&Qh[qrow_a * DH + kk * 32 + 8 * (lane >> 4)]);

  float m_r[4], l_r[4];
  f32x4 o[4] = {};
  #pragma unroll
  for (int r = 0; r < 4; ++r) { m_r[r] = -1e30f; l_r[r] = 0.f; }

  int lastt = q0 + 63;
  if (nf - 1 > lastt) lastt = nf - 1;
  const int ktend = lastt >> 6;

  const int vd = tid & 63;
  const int vt0 = (tid >> 6) * 16;

  for (int kt = 0; kt <= ktend; ++kt) {
    const int kv0 = kt * 64;
    __syncthreads();
    // stage K rows (vectorized copy)
    {
      const int rr = tid >> 3;
      const int sc = (tid & 7) * 8;
      *reinterpret_cast<short8*>(&Ks[rr][sc]) =
        *reinterpret_cast<const short8*>(&Kh[(kv0 + rr) * DH + sc]);
      *reinterpret_cast<short8*>(&Ks[rr + 32][sc]) =
        *reinterpret_cast<const short8*>(&Kh[(kv0 + rr + 32) * DH + sc]);
    }
    // stage V^T: coalesced global column reads, vector LDS row writes
    {
      unsigned short tv[16];
      #pragma unroll
      for (int t = 0; t < 16; ++t)
        tv[t] = Vh[(kv0 + vt0 + t) * DH + vd];
      short8 p0, p1;
      #pragma unroll
      for (int t = 0; t < 8; ++t) { p0[t] = (short)tv[t]; p1[t] = (short)tv[t + 8]; }
      *reinterpret_cast<short8*>(&VTs[vd][vt0]) = p0;
      *reinterpret_cast<short8*>(&VTs[vd][vt0 + 8]) = p1;
    }
    __syncthreads();

    // S = Q K^T
    f32x4 s[4];
    #pragma unroll
    for (int nb = 0; nb < 4; ++nb) {
      f32x4 a = {};
      #pragma unroll
      for (int kk = 0; kk < 2; ++kk) {
        short8 kf = *reinterpret_cast<const short8*>(
            &Ks[nb * 16 + (lane & 15)][kk * 32 + 8 * (lane >> 4)]);
        a = __builtin_amdgcn_mfma_f32_16x16x32_bf16(qf[kk], kf, a, 0, 0, 0);
      }
      s[nb] = a;
    }

    const int rowb = q0 + w * 16 + (lane >> 4) * 4;
    const bool needmask = !((kv0 + 63 <= q0 + w * 16) || (kv0 + 63 < nf));
    #pragma unroll
    for (int nb = 0; nb < 4; ++nb) {
      const int col = kv0 + nb * 16 + (lane & 15);
      #pragma unroll
      for (int r = 0; r < 4; ++r) {
        float v = s[nb][r] * 0.125f;
        if (needmask && !(col <= rowb + r || col < nf)) v = -1e30f;
        s[nb][r] = v;
      }
    }

    // online softmax (row stats across 16-lane groups)
    float vmax[4];
    #pragma unroll
    for (int r = 0; r < 4; ++r) {
      float v = fmaxf(fmaxf(s[0][r], s[1][r]), fmaxf(s[2][r], s[3][r]));
      #pragma unroll
      for (int off = 8; off >= 1; off >>= 1)
        v = fmaxf(v, __shfl_xor(v, off, 64));
      vmax[r] = v;
    }
    float alpha[4];
    #pragma unroll
    for (int r = 0; r < 4; ++r) {
      float mn = fmaxf(m_r[r], vmax[r]);
      alpha[r] = exp2f((m_r[r] - mn) * 1.44269504f);
      m_r[r] = mn;
    }
    float rs[4] = {0.f, 0.f, 0.f, 0.f};
    #pragma unroll
    for (int nb = 0; nb < 4; ++nb) {
      #pragma unroll
      for (int r = 0; r < 4; ++r) {
        float p = exp2f((s[nb][r] - m_r[r]) * 1.44269504f);
        rs[r] += p;
        Ps[w][(lane >> 4) * 4 + r][nb * 16 + (lane & 15)] = f2bf(p);
      }
    }
    #pragma unroll
    for (int r = 0; r < 4; ++r) {
      float v = rs[r];
      #pragma unroll
      for (int off = 8; off >= 1; off >>= 1)
        v += __shfl_xor(v, off, 64);
      l_r[r] = l_r[r] * alpha[r] + v;
    }
    #pragma unroll
    for (int db = 0; db < 4; ++db)
      #pragma unroll
      for (int r = 0; r < 4; ++r)
        o[db][r] *= alpha[r];

    __syncthreads();

    // O += P * V
    #pragma unroll
    for (int kk = 0; kk < 2; ++kk) {
      short8 pa = *reinterpret_cast<const short8*>(
          &Ps[w][lane & 15][kk * 32 + 8 * (lane >> 4)]);
      #pragma unroll
      for (int db = 0; db < 4; ++db) {
        short8 vb = *reinterpret_cast<const short8*>(
            &VTs[db * 16 + (lane & 15)][kk * 32 + 8 * (lane >> 4)]);
        o[db] = __builtin_amdgcn_mfma_f32_16x16x32_bf16(pa, vb, o[db], 0, 0, 0);
      }
    }
  }

  // epilogue: y[t][h*64+d]
  const int orow = q0 + w * 16 + (lane >> 4) * 4;
  const int ocol = h * DH + (lane & 15);
  #pragma unroll
  for (int db = 0; db < 4; ++db) {
    #pragma unroll
    for (int r = 0; r < 4; ++r) {
      float v = o[db][r] / l_r[r];
      y[(orow + r) * Cdim + ocol + db * 16] = f2bf(v);
    }
  }
}

extern "C" void kernel_launch(void* const* d_in, const int* in_sizes, int n_in,
                              void* d_out, int out_size, void* d_ws, size_t ws_size,
                              hipStream_t stream) {
  (void)in_sizes; (void)n_in; (void)out_size; (void)ws_size;
  const float* x  = (const float*)d_in[0];
  const float* wa = (const float*)d_in[1];
  const float* wp = (const float*)d_in[2];
  const int*   nf = (const int*)d_in[3];
  float* out = (float*)d_out;

  char* ws = (char*)d_ws;
  unsigned short* x_bf = (unsigned short*)(ws);                              // 8 MiB
  unsigned short* waT  = (unsigned short*)(ws + (size_t)8  * 1024 * 1024);   // 6 MiB
  unsigned short* wpT  = (unsigned short*)(ws + (size_t)14 * 1024 * 1024);   // 2 MiB
  unsigned short* qkvb = (unsigned short*)(ws + (size_t)16 * 1024 * 1024);   // 24 MiB [3][16][4096][64]
  unsigned short* ybf  = (unsigned short*)(ws + (size_t)40 * 1024 * 1024);   // 8 MiB

  cvt_kernel<<<4096, 256, 0, stream>>>(x, x_bf, Tq * Cdim);
  transpose_cvt<<<dim3(48, 16), 256, 0, stream>>>(wa, waT, 1024, 3072);
  transpose_cvt<<<dim3(16, 16), 256, 0, stream>>>(wp, wpT, 1024, 1024);
  gemm_bt<0><<<dim3(24, 32), 256, 0, stream>>>(x_bf, waT, (void*)qkvb, Tq, 3 * Cdim, Cdim);
  attn_kernel<<<NH * (Tq / 64), 256, 0, stream>>>(qkvb, ybf, nf);
  gemm_bt<1><<<dim3(Cdim / 128, Tq / 128), 256, 0, stream>>>(ybf, wpT, (void*)out, Tq, Cdim, Cdim);
}